// Round 1
// baseline (1611.501 us; speedup 1.0000x reference)
//
#include <hip/hip_runtime.h>

#define NUM_USERS 100000
#define NUM_ITEMS 50000
#define NNZ       2400000
#define EMB       64
#define NTOT      (NUM_USERS + NUM_ITEMS)
#define NQ        16384

// cur = concat(emb_user, emb_item), float4 copy
__global__ void init_cur_kernel(const float* __restrict__ eu,
                                const float* __restrict__ ei,
                                float* __restrict__ cur) {
    int idx = blockIdx.x * blockDim.x + threadIdx.x;           // float4 index
    const int total4 = NTOT * EMB / 4;
    const int user4  = NUM_USERS * EMB / 4;
    if (idx < total4) {
        float4 v;
        if (idx < user4) v = ((const float4*)eu)[idx];
        else             v = ((const float4*)ei)[idx - user4];
        ((float4*)cur)[idx] = v;
    }
}

// one thread per (edge, d); wave (64 lanes) shares one edge
__global__ void spmm_kernel(const int* __restrict__ row,
                            const int* __restrict__ col,
                            const float* __restrict__ val,
                            const float* __restrict__ cur,
                            float* __restrict__ next) {
    long long idx = (long long)blockIdx.x * blockDim.x + threadIdx.x;
    if (idx >= (long long)NNZ * EMB) return;
    int e = (int)(idx >> 6);
    int d = (int)(idx & 63);
    int r = row[e];
    int c = col[e];
    float v = val[e];
    atomicAdd(&next[r * EMB + d], v * cur[c * EMB + d]);
}

// accumulate the 16384 gathered user/item rows
template <bool STORE>
__global__ void gather_acc_kernel(const int* __restrict__ users,
                                  const int* __restrict__ items,
                                  const float* __restrict__ src,
                                  float* __restrict__ uacc,
                                  float* __restrict__ iacc) {
    int idx = blockIdx.x * blockDim.x + threadIdx.x;
    if (idx >= NQ * EMB) return;
    int j = idx >> 6;
    int d = idx & 63;
    int u  = users[j];
    int it = items[j] + NUM_USERS;
    float uv = src[u * EMB + d];
    float iv = src[it * EMB + d];
    if (STORE) { uacc[idx] = uv; iacc[idx] = iv; }
    else       { uacc[idx] += uv; iacc[idx] += iv; }
}

// gamma[j] = dot(uacc[j], iacc[j]) / 16   (acc/4 dot acc/4)
__global__ void dot_kernel(const float* __restrict__ uacc,
                           const float* __restrict__ iacc,
                           float* __restrict__ out) {
    int idx = blockIdx.x * blockDim.x + threadIdx.x;
    int j = idx >> 6;
    if (j >= NQ) return;
    int d = idx & 63;
    float p = uacc[j * EMB + d] * iacc[j * EMB + d];
    #pragma unroll
    for (int o = 32; o > 0; o >>= 1) p += __shfl_down(p, o);
    if (d == 0) out[j] = p * (1.0f / 16.0f);
}

extern "C" void kernel_launch(void* const* d_in, const int* in_sizes, int n_in,
                              void* d_out, int out_size, void* d_ws, size_t ws_size,
                              hipStream_t stream) {
    const int*   row   = (const int*)d_in[0];
    const int*   col   = (const int*)d_in[1];
    const float* val   = (const float*)d_in[2];
    const float* eu    = (const float*)d_in[3];
    const float* ei    = (const float*)d_in[4];
    const int*   users = (const int*)d_in[5];
    const int*   items = (const int*)d_in[6];
    float*       out   = (float*)d_out;

    float* bufA = (float*)d_ws;                         // NTOT*EMB
    float* bufB = bufA + (size_t)NTOT * EMB;            // NTOT*EMB
    float* uacc = bufB + (size_t)NTOT * EMB;            // NQ*EMB
    float* iacc = uacc + (size_t)NQ * EMB;              // NQ*EMB

    // layer 0
    init_cur_kernel<<<(NTOT * EMB / 4 + 255) / 256, 256, 0, stream>>>(eu, ei, bufA);
    gather_acc_kernel<true><<<(NQ * EMB + 255) / 256, 256, 0, stream>>>(users, items, bufA, uacc, iacc);

    float* cur = bufA;
    float* nxt = bufB;
    const long long spmm_threads = (long long)NNZ * EMB;
    for (int l = 0; l < 3; ++l) {
        hipMemsetAsync(nxt, 0, (size_t)NTOT * EMB * sizeof(float), stream);
        spmm_kernel<<<(int)((spmm_threads + 255) / 256), 256, 0, stream>>>(row, col, val, cur, nxt);
        gather_acc_kernel<false><<<(NQ * EMB + 255) / 256, 256, 0, stream>>>(users, items, nxt, uacc, iacc);
        float* t = cur; cur = nxt; nxt = t;
    }

    dot_kernel<<<(NQ * EMB + 255) / 256, 256, 0, stream>>>(uacc, iacc, out);
}

// Round 2
// 965.281 us; speedup vs baseline: 1.6695x; 1.6695x over previous
//
#include <hip/hip_runtime.h>

#define NUM_USERS 100000
#define NUM_ITEMS 50000
#define NNZ       2400000
#define EMB       64
#define NTOT      (NUM_USERS + NUM_ITEMS)
#define NQ        16384
#define SCAN_BS   1024
#define NBLK      ((NTOT + SCAN_BS - 1) / SCAN_BS)   // 147

// ---------- shared small kernels ----------

__global__ void init_cur_kernel(const float* __restrict__ eu,
                                const float* __restrict__ ei,
                                float* __restrict__ cur) {
    int idx = blockIdx.x * blockDim.x + threadIdx.x;           // float4 index
    const int total4 = NTOT * EMB / 4;
    const int user4  = NUM_USERS * EMB / 4;
    if (idx < total4) {
        float4 v;
        if (idx < user4) v = ((const float4*)eu)[idx];
        else             v = ((const float4*)ei)[idx - user4];
        ((float4*)cur)[idx] = v;
    }
}

template <bool STORE>
__global__ void gather_acc_kernel(const int* __restrict__ users,
                                  const int* __restrict__ items,
                                  const float* __restrict__ src,
                                  float* __restrict__ uacc,
                                  float* __restrict__ iacc) {
    int idx = blockIdx.x * blockDim.x + threadIdx.x;
    if (idx >= NQ * EMB) return;
    int j = idx >> 6;
    int d = idx & 63;
    int u  = users[j];
    int it = items[j] + NUM_USERS;
    float uv = src[u * EMB + d];
    float iv = src[it * EMB + d];
    if (STORE) { uacc[idx] = uv; iacc[idx] = iv; }
    else       { uacc[idx] += uv; iacc[idx] += iv; }
}

__global__ void dot_kernel(const float* __restrict__ uacc,
                           const float* __restrict__ iacc,
                           float* __restrict__ out) {
    int idx = blockIdx.x * blockDim.x + threadIdx.x;
    int j = idx >> 6;
    if (j >= NQ) return;
    int d = idx & 63;
    float p = uacc[j * EMB + d] * iacc[j * EMB + d];
    #pragma unroll
    for (int o = 32; o > 0; o >>= 1) p += __shfl_down(p, o);
    if (d == 0) out[j] = p * (1.0f / 16.0f);
}

// ---------- CSR build ----------

__global__ void count_kernel(const int* __restrict__ row, int* __restrict__ cnt) {
    int e = blockIdx.x * blockDim.x + threadIdx.x;
    if (e < NNZ) atomicAdd(&cnt[row[e]], 1);
}

__global__ void scan_partial_kernel(const int* __restrict__ cnt,
                                    int* __restrict__ rowstart,
                                    int* __restrict__ bsum) {
    __shared__ int s[SCAN_BS];
    int t = threadIdx.x;
    int i = blockIdx.x * SCAN_BS + t;
    int x = (i < NTOT) ? cnt[i] : 0;
    s[t] = x;
    __syncthreads();
    for (int o = 1; o < SCAN_BS; o <<= 1) {
        int v = (t >= o) ? s[t - o] : 0;
        __syncthreads();
        s[t] += v;
        __syncthreads();
    }
    if (i < NTOT) rowstart[i] = s[t] - x;          // exclusive within block
    if (t == SCAN_BS - 1) bsum[blockIdx.x] = s[t]; // block total
}

__global__ void scan_bsum_kernel(const int* __restrict__ bsum, int* __restrict__ boff) {
    __shared__ int s[256];
    int t = threadIdx.x;
    int x = (t < NBLK) ? bsum[t] : 0;
    s[t] = x;
    __syncthreads();
    for (int o = 1; o < 256; o <<= 1) {
        int v = (t >= o) ? s[t - o] : 0;
        __syncthreads();
        s[t] += v;
        __syncthreads();
    }
    if (t < NBLK) boff[t] = s[t] - x;              // exclusive
}

__global__ void add_offsets_kernel(int* __restrict__ rowstart,
                                   const int* __restrict__ boff,
                                   int* __restrict__ offs) {
    int i = blockIdx.x * SCAN_BS + threadIdx.x;
    if (i < NTOT) {
        int v = rowstart[i] + boff[blockIdx.x];
        rowstart[i] = v;
        offs[i] = v;
    }
    if (i == 0) rowstart[NTOT] = NNZ;
}

__global__ void scatter_kernel(const int* __restrict__ row,
                               const int* __restrict__ col,
                               const float* __restrict__ val,
                               int* __restrict__ offs,
                               int* __restrict__ scol,
                               float* __restrict__ sval) {
    int e = blockIdx.x * blockDim.x + threadIdx.x;
    if (e >= NNZ) return;
    int r = row[e];
    int p = atomicAdd(&offs[r], 1);
    scol[p] = col[e];
    sval[p] = val[e];
}

// ---------- SpMM: one wave per row, lane d holds acc[d] ----------

__global__ void spmm_csr_kernel(const int* __restrict__ rowstart,
                                const int* __restrict__ scol,
                                const float* __restrict__ sval,
                                const float* __restrict__ cur,
                                float* __restrict__ next) {
    int gid = blockIdx.x * blockDim.x + threadIdx.x;
    int r = gid >> 6;          // wave id = row
    int d = gid & 63;          // lane = embedding dim
    if (r >= NTOT) return;
    int s = rowstart[r];
    int e = rowstart[r + 1];
    float acc = 0.0f;
    for (int i = s; i < e; ++i) {
        int   c = scol[i];     // wave-uniform -> broadcast
        float v = sval[i];
        acc += v * cur[c * EMB + d];   // coalesced 256B gather
    }
    next[r * EMB + d] = acc;   // coalesced 256B store, no atomics
}

// ---------- fallback atomic SpMM (ws too small) ----------

__global__ void spmm_atomic_kernel(const int* __restrict__ row,
                                   const int* __restrict__ col,
                                   const float* __restrict__ val,
                                   const float* __restrict__ cur,
                                   float* __restrict__ next) {
    long long idx = (long long)blockIdx.x * blockDim.x + threadIdx.x;
    if (idx >= (long long)NNZ * EMB) return;
    int e = (int)(idx >> 6);
    int d = (int)(idx & 63);
    atomicAdd(&next[row[e] * EMB + d], val[e] * cur[col[e] * EMB + d]);
}

extern "C" void kernel_launch(void* const* d_in, const int* in_sizes, int n_in,
                              void* d_out, int out_size, void* d_ws, size_t ws_size,
                              hipStream_t stream) {
    const int*   row   = (const int*)d_in[0];
    const int*   col   = (const int*)d_in[1];
    const float* val   = (const float*)d_in[2];
    const float* eu    = (const float*)d_in[3];
    const float* ei    = (const float*)d_in[4];
    const int*   users = (const int*)d_in[5];
    const int*   items = (const int*)d_in[6];
    float*       out   = (float*)d_out;

    // workspace layout
    float* bufA = (float*)d_ws;                          // NTOT*EMB
    float* bufB = bufA + (size_t)NTOT * EMB;             // NTOT*EMB
    float* uacc = bufB + (size_t)NTOT * EMB;             // NQ*EMB
    float* iacc = uacc + (size_t)NQ * EMB;               // NQ*EMB
    float* sval = iacc + (size_t)NQ * EMB;               // NNZ
    int*   scol = (int*)(sval + (size_t)NNZ);            // NNZ
    int*   cnt  = scol + (size_t)NNZ;                    // NTOT (also reused pattern)
    int*   rowstart = cnt + NTOT;                        // NTOT+1
    int*   offs = rowstart + NTOT + 1;                   // NTOT
    int*   bsum = offs + NTOT;                           // NBLK
    int*   boff = bsum + NBLK;                           // NBLK
    size_t needed = (size_t)((char*)(boff + NBLK) - (char*)d_ws);

    init_cur_kernel<<<(NTOT * EMB / 4 + 255) / 256, 256, 0, stream>>>(eu, ei, bufA);
    gather_acc_kernel<true><<<(NQ * EMB + 255) / 256, 256, 0, stream>>>(users, items, bufA, uacc, iacc);

    float* cur = bufA;
    float* nxt = bufB;

    if (ws_size >= needed) {
        // ---- build CSR once ----
        hipMemsetAsync(cnt, 0, NTOT * sizeof(int), stream);
        count_kernel<<<(NNZ + 255) / 256, 256, 0, stream>>>(row, cnt);
        scan_partial_kernel<<<NBLK, SCAN_BS, 0, stream>>>(cnt, rowstart, bsum);
        scan_bsum_kernel<<<1, 256, 0, stream>>>(bsum, boff);
        add_offsets_kernel<<<NBLK, SCAN_BS, 0, stream>>>(rowstart, boff, offs);
        scatter_kernel<<<(NNZ + 255) / 256, 256, 0, stream>>>(row, col, val, offs, scol, sval);

        for (int l = 0; l < 3; ++l) {
            spmm_csr_kernel<<<(NTOT * 64 + 255) / 256, 256, 0, stream>>>(rowstart, scol, sval, cur, nxt);
            gather_acc_kernel<false><<<(NQ * EMB + 255) / 256, 256, 0, stream>>>(users, items, nxt, uacc, iacc);
            float* t = cur; cur = nxt; nxt = t;
        }
    } else {
        // fallback: atomic SpMM (round-1 path)
        const long long spmm_threads = (long long)NNZ * EMB;
        for (int l = 0; l < 3; ++l) {
            hipMemsetAsync(nxt, 0, (size_t)NTOT * EMB * sizeof(float), stream);
            spmm_atomic_kernel<<<(int)((spmm_threads + 255) / 256), 256, 0, stream>>>(row, col, val, cur, nxt);
            gather_acc_kernel<false><<<(NQ * EMB + 255) / 256, 256, 0, stream>>>(users, items, nxt, uacc, iacc);
            float* t = cur; cur = nxt; nxt = t;
        }
    }

    dot_kernel<<<(NQ * EMB + 255) / 256, 256, 0, stream>>>(uacc, iacc, out);
}

// Round 3
// 577.266 us; speedup vs baseline: 2.7916x; 1.6722x over previous
//
#include <hip/hip_runtime.h>

#define NUM_USERS 100000
#define NUM_ITEMS 50000
#define NNZ       2400000
#define EMB       64
#define NTOT      (NUM_USERS + NUM_ITEMS)
#define NQ        16384
#define SCAN_BS   1024
#define NBLK      ((NTOT + SCAN_BS - 1) / SCAN_BS)   // 147

// ---------- shared small kernels ----------

__global__ void init_cur_kernel(const float* __restrict__ eu,
                                const float* __restrict__ ei,
                                float* __restrict__ cur) {
    int idx = blockIdx.x * blockDim.x + threadIdx.x;           // float4 index
    const int total4 = NTOT * EMB / 4;
    const int user4  = NUM_USERS * EMB / 4;
    if (idx < total4) {
        float4 v;
        if (idx < user4) v = ((const float4*)eu)[idx];
        else             v = ((const float4*)ei)[idx - user4];
        ((float4*)cur)[idx] = v;
    }
}

// float4-vectorized: thread = (j, quarter t)
template <bool STORE>
__global__ void gather_acc_kernel(const int* __restrict__ users,
                                  const int* __restrict__ items,
                                  const float* __restrict__ src,
                                  float* __restrict__ uacc,
                                  float* __restrict__ iacc) {
    int idx = blockIdx.x * blockDim.x + threadIdx.x;
    if (idx >= NQ * 16) return;
    int j = idx >> 4;
    int t = idx & 15;
    int u  = users[j];
    int it = items[j] + NUM_USERS;
    float4 uv = ((const float4*)src)[(size_t)u  * 16 + t];
    float4 iv = ((const float4*)src)[(size_t)it * 16 + t];
    float4* up = (float4*)uacc + idx;
    float4* ip = (float4*)iacc + idx;
    if (STORE) { *up = uv; *ip = iv; }
    else {
        float4 a = *up, b = *ip;
        a.x += uv.x; a.y += uv.y; a.z += uv.z; a.w += uv.w;
        b.x += iv.x; b.y += iv.y; b.z += iv.z; b.w += iv.w;
        *up = a; *ip = b;
    }
}

__global__ void dot_kernel(const float* __restrict__ uacc,
                           const float* __restrict__ iacc,
                           float* __restrict__ out) {
    int idx = blockIdx.x * blockDim.x + threadIdx.x;
    int j = idx >> 6;
    if (j >= NQ) return;
    int d = idx & 63;
    float p = uacc[(size_t)j * EMB + d] * iacc[(size_t)j * EMB + d];
    #pragma unroll
    for (int o = 32; o > 0; o >>= 1) p += __shfl_down(p, o);
    if (d == 0) out[j] = p * (1.0f / 16.0f);
}

// ---------- CSR build ----------

__global__ void count_kernel(const int* __restrict__ row, int* __restrict__ cnt) {
    int e = blockIdx.x * blockDim.x + threadIdx.x;
    if (e < NNZ) atomicAdd(&cnt[row[e]], 1);
}

__global__ void scan_partial_kernel(const int* __restrict__ cnt,
                                    int* __restrict__ rowstart,
                                    int* __restrict__ bsum) {
    __shared__ int s[SCAN_BS];
    int t = threadIdx.x;
    int i = blockIdx.x * SCAN_BS + t;
    int x = (i < NTOT) ? cnt[i] : 0;
    s[t] = x;
    __syncthreads();
    for (int o = 1; o < SCAN_BS; o <<= 1) {
        int v = (t >= o) ? s[t - o] : 0;
        __syncthreads();
        s[t] += v;
        __syncthreads();
    }
    if (i < NTOT) rowstart[i] = s[t] - x;          // exclusive within block
    if (t == SCAN_BS - 1) bsum[blockIdx.x] = s[t]; // block total
}

__global__ void scan_bsum_kernel(const int* __restrict__ bsum, int* __restrict__ boff) {
    __shared__ int s[256];
    int t = threadIdx.x;
    int x = (t < NBLK) ? bsum[t] : 0;
    s[t] = x;
    __syncthreads();
    for (int o = 1; o < 256; o <<= 1) {
        int v = (t >= o) ? s[t - o] : 0;
        __syncthreads();
        s[t] += v;
        __syncthreads();
    }
    if (t < NBLK) boff[t] = s[t] - x;              // exclusive
}

__global__ void add_offsets_kernel(int* __restrict__ rowstart,
                                   const int* __restrict__ boff,
                                   int* __restrict__ offs) {
    int i = blockIdx.x * SCAN_BS + threadIdx.x;
    if (i < NTOT) {
        int v = rowstart[i] + boff[blockIdx.x];
        rowstart[i] = v;
        offs[i] = v;
    }
    if (i == 0) rowstart[NTOT] = NNZ;
}

__global__ void scatter_kernel(const int* __restrict__ row,
                               const int* __restrict__ col,
                               const float* __restrict__ val,
                               int* __restrict__ offs,
                               int* __restrict__ scol,
                               float* __restrict__ sval) {
    int e = blockIdx.x * blockDim.x + threadIdx.x;
    if (e >= NNZ) return;
    int r = row[e];
    int p = atomicAdd(&offs[r], 1);
    scol[p] = col[e];
    sval[p] = val[e];
}

// ---------- SpMM: one wave per row; lane = (edge-slot q, dim-quarter t) ----------
// Each gather instruction fetches 4 edges x 256B; 2 gathers in flight per iter;
// col/val for the next iteration prefetched under the gather latency.

__global__ __launch_bounds__(256) void spmm_csr_kernel(
        const int* __restrict__ rowstart,
        const int* __restrict__ scol,
        const float* __restrict__ sval,
        const float* __restrict__ cur,
        float* __restrict__ next) {
    int gid = blockIdx.x * blockDim.x + threadIdx.x;
    int r = gid >> 6;          // wave id = row
    if (r >= NTOT) return;
    int lane = threadIdx.x & 63;
    int q = lane >> 4;         // edge slot 0..3
    int t = lane & 15;         // dim quarter 0..15
    int s = rowstart[r];
    int e = rowstart[r + 1];
    float4 acc = make_float4(0.f, 0.f, 0.f, 0.f);
    if (s < e) {
        int i = s + q;
        int   c0 = scol[(i     < e) ? i     : s];
        float v0 = (i     < e) ? sval[i]     : 0.f;
        int   c1 = scol[(i + 4 < e) ? i + 4 : s];
        float v1 = (i + 4 < e) ? sval[i + 4] : 0.f;
        for (int i0 = s; i0 < e; i0 += 8) {
            int ni = i0 + 8 + q;
            int   nc0 = scol[(ni     < e) ? ni     : s];
            float nv0 = (ni     < e) ? sval[ni]     : 0.f;
            int   nc1 = scol[(ni + 4 < e) ? ni + 4 : s];
            float nv1 = (ni + 4 < e) ? sval[ni + 4] : 0.f;
            float4 g0 = *(const float4*)&cur[(size_t)c0 * EMB + t * 4];
            float4 g1 = *(const float4*)&cur[(size_t)c1 * EMB + t * 4];
            acc.x += v0 * g0.x; acc.y += v0 * g0.y;
            acc.z += v0 * g0.z; acc.w += v0 * g0.w;
            acc.x += v1 * g1.x; acc.y += v1 * g1.y;
            acc.z += v1 * g1.z; acc.w += v1 * g1.w;
            c0 = nc0; v0 = nv0; c1 = nc1; v1 = nv1;
        }
    }
    // reduce across the 4 edge slots (lanes l, l^16, l^32, l^48)
    #pragma unroll
    for (int o = 16; o < 64; o <<= 1) {
        acc.x += __shfl_xor(acc.x, o);
        acc.y += __shfl_xor(acc.y, o);
        acc.z += __shfl_xor(acc.z, o);
        acc.w += __shfl_xor(acc.w, o);
    }
    if (q == 0) ((float4*)&next[(size_t)r * EMB])[t] = acc;
}

// ---------- fallback atomic SpMM (ws too small) ----------

__global__ void spmm_atomic_kernel(const int* __restrict__ row,
                                   const int* __restrict__ col,
                                   const float* __restrict__ val,
                                   const float* __restrict__ cur,
                                   float* __restrict__ next) {
    long long idx = (long long)blockIdx.x * blockDim.x + threadIdx.x;
    if (idx >= (long long)NNZ * EMB) return;
    int e = (int)(idx >> 6);
    int d = (int)(idx & 63);
    atomicAdd(&next[row[e] * EMB + d], val[e] * cur[col[e] * EMB + d]);
}

extern "C" void kernel_launch(void* const* d_in, const int* in_sizes, int n_in,
                              void* d_out, int out_size, void* d_ws, size_t ws_size,
                              hipStream_t stream) {
    const int*   row   = (const int*)d_in[0];
    const int*   col   = (const int*)d_in[1];
    const float* val   = (const float*)d_in[2];
    const float* eu    = (const float*)d_in[3];
    const float* ei    = (const float*)d_in[4];
    const int*   users = (const int*)d_in[5];
    const int*   items = (const int*)d_in[6];
    float*       out   = (float*)d_out;

    // workspace layout
    float* bufA = (float*)d_ws;                          // NTOT*EMB
    float* bufB = bufA + (size_t)NTOT * EMB;             // NTOT*EMB
    float* uacc = bufB + (size_t)NTOT * EMB;             // NQ*EMB
    float* iacc = uacc + (size_t)NQ * EMB;               // NQ*EMB
    float* sval = iacc + (size_t)NQ * EMB;               // NNZ
    int*   scol = (int*)(sval + (size_t)NNZ);            // NNZ
    int*   cnt  = scol + (size_t)NNZ;                    // NTOT
    int*   rowstart = cnt + NTOT;                        // NTOT+1
    int*   offs = rowstart + NTOT + 1;                   // NTOT
    int*   bsum = offs + NTOT;                           // NBLK
    int*   boff = bsum + NBLK;                           // NBLK
    size_t needed = (size_t)((char*)(boff + NBLK) - (char*)d_ws);

    init_cur_kernel<<<(NTOT * EMB / 4 + 255) / 256, 256, 0, stream>>>(eu, ei, bufA);
    gather_acc_kernel<true><<<(NQ * 16 + 255) / 256, 256, 0, stream>>>(users, items, bufA, uacc, iacc);

    float* cur = bufA;
    float* nxt = bufB;

    if (ws_size >= needed) {
        // ---- build CSR once ----
        hipMemsetAsync(cnt, 0, NTOT * sizeof(int), stream);
        count_kernel<<<(NNZ + 255) / 256, 256, 0, stream>>>(row, cnt);
        scan_partial_kernel<<<NBLK, SCAN_BS, 0, stream>>>(cnt, rowstart, bsum);
        scan_bsum_kernel<<<1, 256, 0, stream>>>(bsum, boff);
        add_offsets_kernel<<<NBLK, SCAN_BS, 0, stream>>>(rowstart, boff, offs);
        scatter_kernel<<<(NNZ + 255) / 256, 256, 0, stream>>>(row, col, val, offs, scol, sval);

        for (int l = 0; l < 3; ++l) {
            spmm_csr_kernel<<<(NTOT * 64 + 255) / 256, 256, 0, stream>>>(rowstart, scol, sval, cur, nxt);
            gather_acc_kernel<false><<<(NQ * 16 + 255) / 256, 256, 0, stream>>>(users, items, nxt, uacc, iacc);
            float* t = cur; cur = nxt; nxt = t;
        }
    } else {
        // fallback: atomic SpMM (round-1 path)
        const long long spmm_threads = (long long)NNZ * EMB;
        for (int l = 0; l < 3; ++l) {
            hipMemsetAsync(nxt, 0, (size_t)NTOT * EMB * sizeof(float), stream);
            spmm_atomic_kernel<<<(int)((spmm_threads + 255) / 256), 256, 0, stream>>>(row, col, val, cur, nxt);
            gather_acc_kernel<false><<<(NQ * 16 + 255) / 256, 256, 0, stream>>>(users, items, nxt, uacc, iacc);
            float* t = cur; cur = nxt; nxt = t;
        }
    }

    dot_kernel<<<(NQ * EMB + 255) / 256, 256, 0, stream>>>(uacc, iacc, out);
}

// Round 4
// 565.685 us; speedup vs baseline: 2.8488x; 1.0205x over previous
//
#include <hip/hip_runtime.h>

#define NUM_USERS 100000
#define NUM_ITEMS 50000
#define NNZ       2400000
#define EMB       64
#define NTOT      (NUM_USERS + NUM_ITEMS)
#define NQ        16384
#define SCAN_BS   1024
#define NBLK      ((NTOT + SCAN_BS - 1) / SCAN_BS)   // 147

// ---------- shared small kernels ----------

__global__ void init_cur_kernel(const float* __restrict__ eu,
                                const float* __restrict__ ei,
                                float* __restrict__ cur) {
    int idx = blockIdx.x * blockDim.x + threadIdx.x;           // float4 index
    const int total4 = NTOT * EMB / 4;
    const int user4  = NUM_USERS * EMB / 4;
    if (idx < total4) {
        float4 v;
        if (idx < user4) v = ((const float4*)eu)[idx];
        else             v = ((const float4*)ei)[idx - user4];
        ((float4*)cur)[idx] = v;
    }
}

// float4-vectorized: thread = (j, quarter t)
template <bool STORE>
__global__ void gather_acc_kernel(const int* __restrict__ users,
                                  const int* __restrict__ items,
                                  const float* __restrict__ src,
                                  float* __restrict__ uacc,
                                  float* __restrict__ iacc) {
    int idx = blockIdx.x * blockDim.x + threadIdx.x;
    if (idx >= NQ * 16) return;
    int j = idx >> 4;
    int t = idx & 15;
    int u  = users[j];
    int it = items[j] + NUM_USERS;
    float4 uv = ((const float4*)src)[(size_t)u  * 16 + t];
    float4 iv = ((const float4*)src)[(size_t)it * 16 + t];
    float4* up = (float4*)uacc + idx;
    float4* ip = (float4*)iacc + idx;
    if (STORE) { *up = uv; *ip = iv; }
    else {
        float4 a = *up, b = *ip;
        a.x += uv.x; a.y += uv.y; a.z += uv.z; a.w += uv.w;
        b.x += iv.x; b.y += iv.y; b.z += iv.z; b.w += iv.w;
        *up = a; *ip = b;
    }
}

__global__ void dot_kernel(const float* __restrict__ uacc,
                           const float* __restrict__ iacc,
                           float* __restrict__ out) {
    int idx = blockIdx.x * blockDim.x + threadIdx.x;
    int j = idx >> 6;
    if (j >= NQ) return;
    int d = idx & 63;
    float p = uacc[(size_t)j * EMB + d] * iacc[(size_t)j * EMB + d];
    #pragma unroll
    for (int o = 32; o > 0; o >>= 1) p += __shfl_down(p, o);
    if (d == 0) out[j] = p * (1.0f / 16.0f);
}

// ---------- CSR build ----------

__global__ void count_kernel(const int* __restrict__ row, int* __restrict__ cnt) {
    int e = blockIdx.x * blockDim.x + threadIdx.x;
    if (e < NNZ) atomicAdd(&cnt[row[e]], 1);
}

__global__ void scan_partial_kernel(const int* __restrict__ cnt,
                                    int* __restrict__ rowstart,
                                    int* __restrict__ bsum) {
    __shared__ int s[SCAN_BS];
    int t = threadIdx.x;
    int i = blockIdx.x * SCAN_BS + t;
    int x = (i < NTOT) ? cnt[i] : 0;
    s[t] = x;
    __syncthreads();
    for (int o = 1; o < SCAN_BS; o <<= 1) {
        int v = (t >= o) ? s[t - o] : 0;
        __syncthreads();
        s[t] += v;
        __syncthreads();
    }
    if (i < NTOT) rowstart[i] = s[t] - x;          // exclusive within block
    if (t == SCAN_BS - 1) bsum[blockIdx.x] = s[t]; // block total
}

__global__ void scan_bsum_kernel(const int* __restrict__ bsum, int* __restrict__ boff) {
    __shared__ int s[256];
    int t = threadIdx.x;
    int x = (t < NBLK) ? bsum[t] : 0;
    s[t] = x;
    __syncthreads();
    for (int o = 1; o < 256; o <<= 1) {
        int v = (t >= o) ? s[t - o] : 0;
        __syncthreads();
        s[t] += v;
        __syncthreads();
    }
    if (t < NBLK) boff[t] = s[t] - x;              // exclusive
}

__global__ void add_offsets_kernel(int* __restrict__ rowstart,
                                   const int* __restrict__ boff,
                                   int* __restrict__ offs) {
    int i = blockIdx.x * SCAN_BS + threadIdx.x;
    if (i < NTOT) {
        int v = rowstart[i] + boff[blockIdx.x];
        rowstart[i] = v;
        offs[i] = v;
    }
    if (i == 0) rowstart[NTOT] = NNZ;
}

// packed (col, val) scatter: ONE 8B store per edge instead of two 4B stores
__global__ void scatter_kernel(const int* __restrict__ row,
                               const int* __restrict__ col,
                               const float* __restrict__ val,
                               int* __restrict__ offs,
                               int2* __restrict__ pairs) {
    int e = blockIdx.x * blockDim.x + threadIdx.x;
    if (e >= NNZ) return;
    int r = row[e];
    int p = atomicAdd(&offs[r], 1);
    pairs[p] = make_int2(col[e], __float_as_int(val[e]));
}

// ---------- SpMM: one wave per row; lane = (edge-slot q, dim-quarter t) ----------

__global__ __launch_bounds__(256) void spmm_csr_kernel(
        const int* __restrict__ rowstart,
        const int2* __restrict__ pairs,
        const float* __restrict__ cur,
        float* __restrict__ next) {
    int gid = blockIdx.x * blockDim.x + threadIdx.x;
    int r = gid >> 6;          // wave id = row
    if (r >= NTOT) return;
    int lane = threadIdx.x & 63;
    int q = lane >> 4;         // edge slot 0..3
    int t = lane & 15;         // dim quarter 0..15
    int s = rowstart[r];
    int e = rowstart[r + 1];
    float4 acc = make_float4(0.f, 0.f, 0.f, 0.f);
    if (s < e) {
        int i = s + q;
        int2 cv0 = pairs[(i     < e) ? i     : s];
        int2 cv1 = pairs[(i + 4 < e) ? i + 4 : s];
        float v0 = (i     < e) ? __int_as_float(cv0.y) : 0.f;
        float v1 = (i + 4 < e) ? __int_as_float(cv1.y) : 0.f;
        for (int i0 = s; i0 < e; i0 += 8) {
            int ni = i0 + 8 + q;
            int2 ncv0 = pairs[(ni     < e) ? ni     : s];
            int2 ncv1 = pairs[(ni + 4 < e) ? ni + 4 : s];
            float nv0 = (ni     < e) ? __int_as_float(ncv0.y) : 0.f;
            float nv1 = (ni + 4 < e) ? __int_as_float(ncv1.y) : 0.f;
            float4 g0 = *(const float4*)&cur[(size_t)cv0.x * EMB + t * 4];
            float4 g1 = *(const float4*)&cur[(size_t)cv1.x * EMB + t * 4];
            acc.x += v0 * g0.x; acc.y += v0 * g0.y;
            acc.z += v0 * g0.z; acc.w += v0 * g0.w;
            acc.x += v1 * g1.x; acc.y += v1 * g1.y;
            acc.z += v1 * g1.z; acc.w += v1 * g1.w;
            cv0 = ncv0; v0 = nv0; cv1 = ncv1; v1 = nv1;
        }
    }
    // reduce across the 4 edge slots (lanes l, l^16, l^32, l^48)
    #pragma unroll
    for (int o = 16; o < 64; o <<= 1) {
        acc.x += __shfl_xor(acc.x, o);
        acc.y += __shfl_xor(acc.y, o);
        acc.z += __shfl_xor(acc.z, o);
        acc.w += __shfl_xor(acc.w, o);
    }
    if (q == 0) ((float4*)&next[(size_t)r * EMB])[t] = acc;
}

// ---------- fallback atomic SpMM (ws too small) ----------

__global__ void spmm_atomic_kernel(const int* __restrict__ row,
                                   const int* __restrict__ col,
                                   const float* __restrict__ val,
                                   const float* __restrict__ cur,
                                   float* __restrict__ next) {
    long long idx = (long long)blockIdx.x * blockDim.x + threadIdx.x;
    if (idx >= (long long)NNZ * EMB) return;
    int e = (int)(idx >> 6);
    int d = (int)(idx & 63);
    atomicAdd(&next[row[e] * EMB + d], val[e] * cur[col[e] * EMB + d]);
}

extern "C" void kernel_launch(void* const* d_in, const int* in_sizes, int n_in,
                              void* d_out, int out_size, void* d_ws, size_t ws_size,
                              hipStream_t stream) {
    const int*   row   = (const int*)d_in[0];
    const int*   col   = (const int*)d_in[1];
    const float* val   = (const float*)d_in[2];
    const float* eu    = (const float*)d_in[3];
    const float* ei    = (const float*)d_in[4];
    const int*   users = (const int*)d_in[5];
    const int*   items = (const int*)d_in[6];
    float*       out   = (float*)d_out;

    // workspace layout
    float* bufA = (float*)d_ws;                          // NTOT*EMB
    float* bufB = bufA + (size_t)NTOT * EMB;             // NTOT*EMB
    float* uacc = bufB + (size_t)NTOT * EMB;             // NQ*EMB
    float* iacc = uacc + (size_t)NQ * EMB;               // NQ*EMB
    int2*  pairs = (int2*)(iacc + (size_t)NQ * EMB);     // NNZ int2 (8B aligned)
    int*   cnt  = (int*)(pairs + (size_t)NNZ);           // NTOT
    int*   rowstart = cnt + NTOT;                        // NTOT+1
    int*   offs = rowstart + NTOT + 1;                   // NTOT
    int*   bsum = offs + NTOT;                           // NBLK
    int*   boff = bsum + NBLK;                           // NBLK
    size_t needed = (size_t)((char*)(boff + NBLK) - (char*)d_ws);

    init_cur_kernel<<<(NTOT * EMB / 4 + 255) / 256, 256, 0, stream>>>(eu, ei, bufA);
    gather_acc_kernel<true><<<(NQ * 16 + 255) / 256, 256, 0, stream>>>(users, items, bufA, uacc, iacc);

    float* cur = bufA;
    float* nxt = bufB;

    if (ws_size >= needed) {
        // ---- build CSR once ----
        hipMemsetAsync(cnt, 0, NTOT * sizeof(int), stream);
        count_kernel<<<(NNZ + 255) / 256, 256, 0, stream>>>(row, cnt);
        scan_partial_kernel<<<NBLK, SCAN_BS, 0, stream>>>(cnt, rowstart, bsum);
        scan_bsum_kernel<<<1, 256, 0, stream>>>(bsum, boff);
        add_offsets_kernel<<<NBLK, SCAN_BS, 0, stream>>>(rowstart, boff, offs);
        scatter_kernel<<<(NNZ + 255) / 256, 256, 0, stream>>>(row, col, val, offs, pairs);

        for (int l = 0; l < 3; ++l) {
            spmm_csr_kernel<<<(NTOT * 64 + 255) / 256, 256, 0, stream>>>(rowstart, pairs, cur, nxt);
            gather_acc_kernel<false><<<(NQ * 16 + 255) / 256, 256, 0, stream>>>(users, items, nxt, uacc, iacc);
            float* t = cur; cur = nxt; nxt = t;
        }
    } else {
        // fallback: atomic SpMM (round-1 path)
        const long long spmm_threads = (long long)NNZ * EMB;
        for (int l = 0; l < 3; ++l) {
            hipMemsetAsync(nxt, 0, (size_t)NTOT * EMB * sizeof(float), stream);
            spmm_atomic_kernel<<<(int)((spmm_threads + 255) / 256), 256, 0, stream>>>(row, col, val, cur, nxt);
            gather_acc_kernel<false><<<(NQ * 16 + 255) / 256, 256, 0, stream>>>(users, items, nxt, uacc, iacc);
            float* t = cur; cur = nxt; nxt = t;
        }
    }

    dot_kernel<<<(NQ * EMB + 255) / 256, 256, 0, stream>>>(uacc, iacc, out);
}